// Round 3
// baseline (781.711 us; speedup 1.0000x reference)
//
#include <hip/hip_runtime.h>
#include <hip/hip_fp16.h>
#include <math.h>

// B=16, N=16384, C_IN=C_OUT=128, K=9
#define B_ 16
#define N_ 16384
#define C_ 128
#define K_ 9
#define FCONV 1152           // K_*C_
#define FPAD 1160            // flat row stride in halfs: 16B-aligned, bank-friendly (measured 0 conflicts)
#define LDS_BYTES (B_ * FPAD * 2)   // 37120 B dynamic LDS (G=1) -> 4 blocks/CU

typedef _Float16 half8 __attribute__((ext_vector_type(8)));
typedef float floatx4 __attribute__((ext_vector_type(4)));

__device__ __forceinline__ float elu_f(float v) {
    return v > 0.f ? v : (__expf(v) - 1.f);
}

// ---- prep 1: x (B,N,C) fp32 -> f16 copy in d_ws ----
__global__ __launch_bounds__(256) void convert_x(const float* __restrict__ x,
                                                 _Float16* __restrict__ xh) {
    const size_t i = ((size_t)blockIdx.x * 256 + threadIdx.x) * 8;   // 8 elems/thread
    const float4 a = *(const float4*)(x + i);
    const float4 b = *(const float4*)(x + i + 4);
    half8 h = {(_Float16)a.x, (_Float16)a.y, (_Float16)a.z, (_Float16)a.w,
               (_Float16)b.x, (_Float16)b.y, (_Float16)b.z, (_Float16)b.w};
    *(half8*)(xh + i) = h;
}

// ---- prep 2: W -> MFMA b-fragment-major f16 (same layout as round 2) ----
__global__ void build_wfrag(const float* __restrict__ Wc, const float* __restrict__ Ws,
                            _Float16* __restrict__ WcF, _Float16* __restrict__ WsF) {
    const int i = blockIdx.x * 256 + threadIdx.x;
    if (i < 8 * 36 * 64 * 8) {
        const int j = i & 7, lane = (i >> 3) & 63;
        const int rest = i >> 9;               // ot*36 + kc
        const int kc = rest % 36, ot = rest / 36;
        WcF[i] = (_Float16)Wc[(size_t)(ot * 16 + (lane & 15)) * FCONV + kc * 32 + (lane >> 4) * 8 + j];
    }
    if (i < 8 * 4 * 64 * 8) {
        const int j = i & 7, lane = (i >> 3) & 63;
        const int rest = i >> 9;               // ot*4 + kc
        const int kc = rest & 3, ot = rest >> 2;
        WsF[i] = (_Float16)Ws[(size_t)(ot * 16 + (lane & 15)) * C_ + kc * 32 + (lane >> 4) * 8 + j];
    }
}

// WF16: W pre-swizzled f16 frags in ws.  XH: x pre-converted f16 in ws.
template <bool WF16, bool XH>
__global__ __launch_bounds__(256, 4) void paiconv_mfma(
    const float*    __restrict__ x,    // (B,N,C) fp32
    const _Float16* __restrict__ xh,   // (B,N,C) f16 (XH only)
    const int*      __restrict__ idx,  // (N,K)
    const float*    __restrict__ P,    // (N,K,K)
    const void*     __restrict__ WcP,
    const float*    __restrict__ bc,
    const void*     __restrict__ WsP,
    const float*    __restrict__ bs,
    float*          __restrict__ out)  // (B,N,C_OUT)
{
    extern __shared__ _Float16 flat_s[];   // [16][FPAD] f16
    __shared__ float P_s[81];
    __shared__ int   idx_s[K_];

    const int tid = threadIdx.x;
    const int n   = blockIdx.x;

    if (tid < 81) P_s[tid] = P[(size_t)n * 81 + tid];
    if (tid < K_) idx_s[tid] = idx[(size_t)n * K_ + tid];
    __syncthreads();

    // ---------------- phase 1: gather + P-mix + ELU -> flat_s (f16) ----------------
    {
        const int c = tid & (C_ - 1);
        const int h = tid >> 7;                 // 0/1 -> batches [0..8) / [8..16)
        int id[K_];
        #pragma unroll
        for (int j = 0; j < K_; ++j) id[j] = idx_s[j];

        #pragma unroll
        for (int q = 0; q < 2; ++q) {           // two quads of 4 batches: 36 loads in flight
            float v[4][K_];
            #pragma unroll
            for (int i = 0; i < 4; ++i) {
                const int m = h * 8 + q * 4 + i;
                if (XH) {
                    const _Float16* xb = xh + (size_t)m * (N_ * C_) + c;
                    #pragma unroll
                    for (int j = 0; j < K_; ++j)
                        v[i][j] = ((unsigned)id[j] < (unsigned)N_) ? (float)xb[(size_t)id[j] * C_] : 0.f;
                } else {
                    const float* xb = x + (size_t)m * (N_ * C_) + c;
                    #pragma unroll
                    for (int j = 0; j < K_; ++j)
                        v[i][j] = ((unsigned)id[j] < (unsigned)N_) ? xb[(size_t)id[j] * C_] : 0.f;
                }
            }
            #pragma unroll
            for (int k = 0; k < K_; ++k) {
                float pr[K_];
                #pragma unroll
                for (int j = 0; j < K_; ++j) pr[j] = P_s[k * K_ + j];
                #pragma unroll
                for (int i = 0; i < 4; ++i) {
                    float s = 0.f;
                    #pragma unroll
                    for (int j = 0; j < K_; ++j) s = fmaf(pr[j], v[i][j], s);
                    flat_s[(h * 8 + q * 4 + i) * FPAD + k * C_ + c] = (_Float16)elu_f(s);
                }
            }
        }
    }
    __syncthreads();

    // ---------------- phase 2: MFMA GEMMs ----------------
    const int w    = tid >> 6;
    const int lane = tid & 63;
    const int col  = lane & 15;
    const int quad = lane >> 4;
    const int o0   = w * 32;         // wave covers output cols [o0, o0+32)

    floatx4 accC[2], accS[2];
    #pragma unroll
    for (int t = 0; t < 2; ++t) {
        accC[t] = (floatx4){0.f, 0.f, 0.f, 0.f};
        accS[t] = (floatx4){0.f, 0.f, 0.f, 0.f};
    }

    // conv GEMM: flat (16 x 1152) @ Wc^T -> 16x128
    for (int k0 = 0; k0 < FCONV; k0 += 32) {
        const half8 a = *(const half8*)&flat_s[col * FPAD + k0 + quad * 8];
        #pragma unroll
        for (int t = 0; t < 2; ++t) {
            half8 b;
            if (WF16) {
                b = ((const half8*)WcP)[((w * 2 + t) * 36 + (k0 >> 5)) * 64 + lane];
            } else {
                const float* p = (const float*)WcP + (size_t)(o0 + t * 16 + col) * FCONV + k0 + quad * 8;
                const float4 w0 = *(const float4*)p;
                const float4 w1 = *(const float4*)(p + 4);
                b = (half8){(_Float16)w0.x, (_Float16)w0.y, (_Float16)w0.z, (_Float16)w0.w,
                            (_Float16)w1.x, (_Float16)w1.y, (_Float16)w1.z, (_Float16)w1.w};
            }
            accC[t] = __builtin_amdgcn_mfma_f32_16x16x32_f16(a, b, accC[t], 0, 0, 0);
        }
    }

    // skip GEMM: x row n (16 x 128) @ Ws^T; A-frags direct from global
    for (int k0 = 0; k0 < C_; k0 += 32) {
        half8 a;
        if (XH) {
            a = *(const half8*)(xh + (size_t)col * (N_ * C_) + (size_t)n * C_ + k0 + quad * 8);
        } else {
            const float* p = x + (size_t)col * (N_ * C_) + (size_t)n * C_ + k0 + quad * 8;
            const float4 x0 = *(const float4*)p;
            const float4 x1 = *(const float4*)(p + 4);
            a = (half8){(_Float16)x0.x, (_Float16)x0.y, (_Float16)x0.z, (_Float16)x0.w,
                        (_Float16)x1.x, (_Float16)x1.y, (_Float16)x1.z, (_Float16)x1.w};
        }
        #pragma unroll
        for (int t = 0; t < 2; ++t) {
            half8 b;
            if (WF16) {
                b = ((const half8*)WsP)[((w * 2 + t) * 4 + (k0 >> 5)) * 64 + lane];
            } else {
                const float* p = (const float*)WsP + (size_t)(o0 + t * 16 + col) * C_ + k0 + quad * 8;
                const float4 w0 = *(const float4*)p;
                const float4 w1 = *(const float4*)(p + 4);
                b = (half8){(_Float16)w0.x, (_Float16)w0.y, (_Float16)w0.z, (_Float16)w0.w,
                            (_Float16)w1.x, (_Float16)w1.y, (_Float16)w1.z, (_Float16)w1.w};
            }
            accS[t] = __builtin_amdgcn_mfma_f32_16x16x32_f16(a, b, accS[t], 0, 0, 0);
        }
    }

    // ---------------- epilogue ----------------
    #pragma unroll
    for (int t = 0; t < 2; ++t) {
        const int o = o0 + t * 16 + col;
        const float bcv = bc[o];
        const float bsv = bs[o];
        #pragma unroll
        for (int r = 0; r < 4; ++r) {
            const int m = quad * 4 + r;     // C/D: row = (lane>>4)*4 + reg
            const float z = elu_f(accC[t][r] + bcv);
            out[((size_t)m * N_ + n) * C_ + o] = z + accS[t][r] + bsv;
        }
    }
}

extern "C" void kernel_launch(void* const* d_in, const int* in_sizes, int n_in,
                              void* d_out, int out_size, void* d_ws, size_t ws_size,
                              hipStream_t stream) {
    const float* x   = (const float*)d_in[0];
    const int*   idx = (const int*)  d_in[1];
    const float* P   = (const float*)d_in[2];
    const float* Wc  = (const float*)d_in[3];
    const float* bc  = (const float*)d_in[4];
    const float* Ws  = (const float*)d_in[5];
    const float* bs  = (const float*)d_in[6];
    float* out = (float*)d_out;

    const size_t wc_halfs = (size_t)8 * 36 * 64 * 8;     // 147456
    const size_t ws_halfs = (size_t)8 * 4 * 64 * 8;      // 16384
    const size_t xh_halfs = (size_t)B_ * N_ * C_;        // 33554432 (64 MiB)
    const size_t need_w  = (wc_halfs + ws_halfs) * sizeof(_Float16);
    const size_t need_wx = need_w + xh_halfs * sizeof(_Float16);

    if (ws_size >= need_wx) {
        _Float16* WcF = (_Float16*)d_ws;
        _Float16* WsF = WcF + wc_halfs;
        _Float16* xh  = WsF + ws_halfs;
        build_wfrag<<<dim3(576), dim3(256), 0, stream>>>(Wc, Ws, WcF, WsF);
        convert_x<<<dim3((int)(xh_halfs / 2048)), dim3(256), 0, stream>>>(x, xh);
        hipFuncSetAttribute((const void*)paiconv_mfma<true, true>,
                            hipFuncAttributeMaxDynamicSharedMemorySize, LDS_BYTES);
        paiconv_mfma<true, true><<<dim3(N_), dim3(256), LDS_BYTES, stream>>>(
            x, xh, idx, P, WcF, bc, WsF, bs, out);
    } else if (ws_size >= need_w) {
        _Float16* WcF = (_Float16*)d_ws;
        _Float16* WsF = WcF + wc_halfs;
        build_wfrag<<<dim3(576), dim3(256), 0, stream>>>(Wc, Ws, WcF, WsF);
        hipFuncSetAttribute((const void*)paiconv_mfma<true, false>,
                            hipFuncAttributeMaxDynamicSharedMemorySize, LDS_BYTES);
        paiconv_mfma<true, false><<<dim3(N_), dim3(256), LDS_BYTES, stream>>>(
            x, nullptr, idx, P, WcF, bc, WsF, bs, out);
    } else {
        hipFuncSetAttribute((const void*)paiconv_mfma<false, false>,
                            hipFuncAttributeMaxDynamicSharedMemorySize, LDS_BYTES);
        paiconv_mfma<false, false><<<dim3(N_), dim3(256), LDS_BYTES, stream>>>(
            x, nullptr, idx, P, Wc, bc, Ws, bs, out);
    }
}